// Round 3
// baseline (210.862 us; speedup 1.0000x reference)
//
#include <hip/hip_runtime.h>
#include <math.h>

// ---- problem constants ----
#define NPIX 12544            // 64*14*14 pixels
#define CIN  2048
#define NB   64               // batch
#define PPIX 196              // pixels per batch image
#define NWV  8                // K-split waves per block (K=256 each)
#define PCH  7                // pixel chunks in gap (28 pixels each)

typedef short  bf16x8 __attribute__((ext_vector_type(8)));
typedef float  f32x4  __attribute__((ext_vector_type(4)));

__device__ inline unsigned short f2bf(float f) {
    unsigned int u = __float_as_uint(f);
    u = (u + 0x7fffu + ((u >> 16) & 1u)) >> 16;
    return (unsigned short)u;
}

// ---- kernel 0: transpose+convert W1 [2048][64] f32 -> W1t [64][2048] bf16 ----
__global__ __launch_bounds__(256) void conv_w1(
    const float* __restrict__ W1, unsigned short* __restrict__ W1t)
{
    const int id = blockIdx.x * 256 + threadIdx.x;   // 0..131071
    const int n = id >> 11;
    const int k = id & 2047;
    W1t[id] = f2bf(W1[k * 64 + n]);
}

// ---- kernel 1: a_p = sigmoid(MLP(x_p)), layer 1 via bf16 MFMA ----
// 784 blocks x 512 threads (8 waves). Wave wv handles K slice [wv*256,+256)
// of the 16x64 h1 tile; partials K-reduced in LDS; 16 lanes run the tail.
__global__ __launch_bounds__(512) void attn_scores_mfma(
    const float* __restrict__ x, const unsigned short* __restrict__ W1t,
    const float* __restrict__ b1,
    const float* __restrict__ W2, const float* __restrict__ b2,
    const float* __restrict__ W3, const float* __restrict__ b3,
    const float* __restrict__ W4, const float* __restrict__ b4,
    float* __restrict__ a_out)
{
    __shared__ float part[NWV][16][68];  // stride 68: q-groups alias only 2-way
    __shared__ float h1s[16][68];

    const int tid  = threadIdx.x;
    const int lane = tid & 63;
    const int wv   = tid >> 6;           // 0..7
    const int l15  = lane & 15;          // pixel row (A) / channel col (B)
    const int q    = lane >> 4;          // k-quad
    const size_t pix0 = (size_t)blockIdx.x * 16;

    const int kb = wv * (CIN / NWV);     // 256-wide K slice
    const float* xr = x + (pix0 + l15) * (size_t)CIN + kb + q * 8;
    const unsigned short* wr = W1t + (size_t)l15 * CIN + kb + q * 8;

    f32x4 acc[4] = {{0,0,0,0},{0,0,0,0},{0,0,0,0},{0,0,0,0}};

#pragma unroll
    for (int k0 = 0; k0 < CIN / NWV; k0 += 32) {
        float4 xa = *(const float4*)(xr + k0);
        float4 xb = *(const float4*)(xr + k0 + 4);
        bf16x8 af;
        af[0] = (short)f2bf(xa.x); af[1] = (short)f2bf(xa.y);
        af[2] = (short)f2bf(xa.z); af[3] = (short)f2bf(xa.w);
        af[4] = (short)f2bf(xb.x); af[5] = (short)f2bf(xb.y);
        af[6] = (short)f2bf(xb.z); af[7] = (short)f2bf(xb.w);
#pragma unroll
        for (int ct = 0; ct < 4; ++ct) {
            bf16x8 bfr = *(const bf16x8*)(wr + (size_t)ct * 16 * CIN + k0);
            acc[ct] = __builtin_amdgcn_mfma_f32_16x16x32_bf16(af, bfr, acc[ct], 0, 0, 0);
        }
    }

    // C/D: col = l15 (channel-in-tile), row = q*4 + reg (pixel)
#pragma unroll
    for (int ct = 0; ct < 4; ++ct)
#pragma unroll
        for (int r = 0; r < 4; ++r)
            part[wv][q * 4 + r][ct * 16 + l15] = acc[ct][r];
    __syncthreads();

    // K-reduce 8 partials + bias + relu -> h1s. 1024 elems / 512 threads.
#pragma unroll
    for (int e = tid; e < 16 * 64; e += 512) {
        const int m = e >> 6, n = e & 63;
        float v = b1[n];
#pragma unroll
        for (int w = 0; w < NWV; ++w) v += part[w][m][n];
        h1s[m][n] = fmaxf(v, 0.f);
    }
    __syncthreads();

    // tail: 16 threads, one pixel each (~1.2 kFLOP)
    if (tid < 16) {
        float hv[64];
#pragma unroll
        for (int i = 0; i < 16; ++i) {
            float4 t = *(const float4*)&h1s[tid][i * 4];
            hv[i*4+0] = t.x; hv[i*4+1] = t.y; hv[i*4+2] = t.z; hv[i*4+3] = t.w;
        }
        float h2[16];
#pragma unroll
        for (int j = 0; j < 16; ++j) {
            float s = b2[j];
#pragma unroll
            for (int k = 0; k < 64; ++k) s = fmaf(hv[k], W2[k * 16 + j], s);
            h2[j] = fmaxf(s, 0.f);
        }
        float h3[8];
#pragma unroll
        for (int j = 0; j < 8; ++j) {
            float s = b3[j];
#pragma unroll
            for (int k = 0; k < 16; ++k) s = fmaf(h2[k], W3[k * 8 + j], s);
            h3[j] = fmaxf(s, 0.f);
        }
        float z = b4[0];
#pragma unroll
        for (int k = 0; k < 8; ++k) z = fmaf(h3[k], W4[k], z);
        a_out[pix0 + tid] = 1.f / (1.f + expf(-z));
    }
}

// ---- kernel 2: partial weighted sums. grid (2 c-half, 64 b, 7 p-chunk) ----
__global__ __launch_bounds__(256) void gap_partial(
    const float* __restrict__ x, const float* __restrict__ a,
    float* __restrict__ part)
{
    const int b  = blockIdx.y;
    const int pz = blockIdx.z;                       // 0..6 (28 pixels each)
    const int c0 = blockIdx.x * 1024 + threadIdx.x * 4;
    const float* xb = x + ((size_t)b * PPIX + pz * 28) * CIN + c0;
    const float* ab = a + b * PPIX + pz * 28;

    float4 s0 = {0,0,0,0}, s1 = {0,0,0,0};
#pragma unroll 4
    for (int p = 0; p < 28; p += 2) {
        const float a0 = ab[p], a1 = ab[p + 1];
        const float4 v0 = *(const float4*)(xb + (size_t)p * CIN);
        const float4 v1 = *(const float4*)(xb + (size_t)(p + 1) * CIN);
        s0.x = fmaf(a0, v0.x, s0.x); s0.y = fmaf(a0, v0.y, s0.y);
        s0.z = fmaf(a0, v0.z, s0.z); s0.w = fmaf(a0, v0.w, s0.w);
        s1.x = fmaf(a1, v1.x, s1.x); s1.y = fmaf(a1, v1.y, s1.y);
        s1.z = fmaf(a1, v1.z, s1.z); s1.w = fmaf(a1, v1.w, s1.w);
    }
    float4 r;
    r.x = s0.x + s1.x; r.y = s0.y + s1.y; r.z = s0.z + s1.z; r.w = s0.w + s1.w;
    *(float4*)(part + ((size_t)pz * NB + b) * CIN + c0) = r;
}

// ---- kernel 3: finalize. grid 64, block 512. ----
__global__ __launch_bounds__(512) void gap_final(
    const float* __restrict__ a, const float* __restrict__ part,
    float* __restrict__ out)
{
    __shared__ float red[512];
    const int b = blockIdx.x, t = threadIdx.x;
    red[t] = (t < PPIX) ? a[b * PPIX + t] : 0.f;
    __syncthreads();
#pragma unroll
    for (int s = 256; s > 0; s >>= 1) {
        if (t < s) red[t] += red[t + s];
        __syncthreads();
    }
    const float inv = 1.f / red[0];
    const int c0 = t * 4;
    float4 r = {0,0,0,0};
#pragma unroll
    for (int pz = 0; pz < PCH; ++pz) {
        const float4 p = *(const float4*)(part + ((size_t)pz * NB + b) * CIN + c0);
        r.x += p.x; r.y += p.y; r.z += p.z; r.w += p.w;
    }
    r.x *= inv; r.y *= inv; r.z *= inv; r.w *= inv;
    *(float4*)(out + (size_t)b * CIN + c0) = r;
}

extern "C" void kernel_launch(void* const* d_in, const int* in_sizes, int n_in,
                              void* d_out, int out_size, void* d_ws, size_t ws_size,
                              hipStream_t stream)
{
    const float* x  = (const float*)d_in[0];
    const float* W1 = (const float*)d_in[1];
    const float* b1 = (const float*)d_in[2];
    const float* W2 = (const float*)d_in[3];
    const float* b2 = (const float*)d_in[4];
    const float* W3 = (const float*)d_in[5];
    const float* b3 = (const float*)d_in[6];
    const float* W4 = (const float*)d_in[7];
    const float* b4 = (const float*)d_in[8];
    float* out = (float*)d_out;

    // ws: W1t bf16 [64][2048] @0 (256KB) | a f32 [12544] @256KB |
    //     part f32 [7][64][2048] @512KB (3.5MB)
    unsigned short* W1t = (unsigned short*)d_ws;
    float* a    = (float*)((char*)d_ws + (256 << 10));
    float* part = (float*)((char*)d_ws + (512 << 10));

    conv_w1<<<512, 256, 0, stream>>>(W1, W1t);
    attn_scores_mfma<<<NPIX / 16, 512, 0, stream>>>(x, W1t, b1, W2, b2, W3, b3, W4, b4, a);
    gap_partial<<<dim3(2, NB, PCH), 256, 0, stream>>>(x, a, part);
    gap_final<<<NB, 512, 0, stream>>>(a, part, out);
}